// Round 6
// baseline (57.081 us; speedup 1.0000x reference)
//
#include <hip/hip_runtime.h>

#define NFEAT   100000
#define NBATCH  256
#define DIM     128
#define MARGIN_F 0.5f
#define BN      128                       // feature rows per block
#define NBLK    ((NFEAT + BN - 1) / BN)   // 782
#define CROWS   16                        // feature rows per staged chunk
#define NCHUNK  (BN / CROWS)              // 8
#define NBUF    4                         // pipeline depth (LDS buffers)
#define CBYTES  (CROWS * DIM * 4)         // 8 KiB per chunk
#define FLT_BIG 3.402823466e+38f

typedef __bf16 bf8_t  __attribute__((ext_vector_type(8)));
typedef short  sh8_t  __attribute__((ext_vector_type(8)));
typedef float  f32x4  __attribute__((ext_vector_type(4)));

// f32 -> bf16 native cast: compiler emits v_cvt_pk_bf16_f32 pairs (RTNE).
__device__ __forceinline__ bf8_t pack8(float4 v0, float4 v1) {
  bf8_t r;
  r[0] = (__bf16)v0.x; r[1] = (__bf16)v0.y; r[2] = (__bf16)v0.z; r[3] = (__bf16)v0.w;
  r[4] = (__bf16)v1.x; r[5] = (__bf16)v1.y; r[6] = (__bf16)v1.z; r[7] = (__bf16)v1.w;
  return r;
}

// MFMA dispatch: works whether the builtin takes bf16-vectors or short-vectors
template <typename VA, typename VC>
__device__ __forceinline__ auto mfma_sel(VA a, VA b, VC c, int)
    -> decltype(__builtin_amdgcn_mfma_f32_16x16x32_bf16(a, b, c, 0, 0, 0)) {
  return __builtin_amdgcn_mfma_f32_16x16x32_bf16(a, b, c, 0, 0, 0);
}
template <typename VA, typename VC>
__device__ __forceinline__ VC mfma_sel(VA a, VA b, VC c, long) {
  return __builtin_amdgcn_mfma_f32_16x16x32_bf16(
      __builtin_bit_cast(sh8_t, a), __builtin_bit_cast(sh8_t, b), c, 0, 0, 0);
}
__device__ __forceinline__ f32x4 mfma_bf16(bf8_t a, bf8_t b, f32x4 c) {
  return mfma_sel(a, b, c, 0);
}

#if defined(__has_builtin)
#if __has_builtin(__builtin_amdgcn_global_load_lds)
#define HAVE_GLLDS 1
#endif
#endif

// 16B global -> LDS async DMA (no VGPR round-trip; counted by vmcnt).
__device__ __forceinline__ void stage16(const char* g, char* l) {
#ifdef HAVE_GLLDS
  __builtin_amdgcn_global_load_lds(
      (const __attribute__((address_space(1))) unsigned int*)g,
      (__attribute__((address_space(3))) unsigned int*)l, 16, 0, 0);
#else
  *reinterpret_cast<float4*>(l) = *reinterpret_cast<const float4*>(g);
#endif
}

#define WAITVM(N) asm volatile("s_waitcnt vmcnt(" #N ")" ::: "memory")
#define CFENCE()  asm volatile("" ::: "memory")

// Kernel 1: fused GEMM + masked min/max partial reduction, counted-vmcnt
// software pipeline (T4): 4 LDS chunk buffers, loads stay in flight across
// barriers (vmcnt never drained to 0 in the main loop).
// Block b: feature rows [b*128, b*128+128) in 8 chunks of 16. 8 waves; wave w
// owns batch rows [32w, 32w+32) (2 M-tiles). A-frags in VGPRs (staged per
// M-tile: max 8 float4 in flight -> no spills under the 128-VGPR cap).
// B staged f32 via global_load_lds with pre-swizzled source (linear LDS dest,
// rule 21); reads undo the XOR (byte ^= (row&7)<<4).
// MFMA 16x16x32 layouts (guide §3, m89/m91-verified):
//   A: lane l holds A[m0 + (l&15)][k0 + (l>>4)*8 + e]
//   B: lane l holds B[k0 + (l>>4)*8 + e][j0 + (l&15)]   (= features[j][k])
//   D: lane l reg r = sim[m0 + (l>>4)*4 + r][j0 + (l&15)]
__global__ __launch_bounds__(512, 4) void triplet_partial(
    const float* __restrict__ inputs, const float* __restrict__ features,
    const int* __restrict__ targets, const int* __restrict__ flabels,
    const int* __restrict__ idx,
    float* __restrict__ ppos, float* __restrict__ pneg)
{
  __shared__ char sbuf[NBUF][CBYTES];   // 32 KiB
  __shared__ int  slab[BN];             // labels for this block's 128 rows

  const int tid  = threadIdx.x;
  const int lane = tid & 63;
  const int wv   = tid >> 6;      // 0..7
  const int l15  = lane & 15;
  const int lg   = lane >> 4;     // 0..3
  const int m0   = wv * 32;
  const int blk  = blockIdx.x;
  const int jbase = blk * BN;

  // stage one 16-row chunk: 1 x 16B per thread, linear LDS dest,
  // pre-swizzled global source (inverse of the read-side XOR).
  auto stage_chunk = [&](int buf, int c) {
    const int p    = tid * 16;                    // LDS byte within chunk
    const int prow = p >> 9;                      // 0..15
    int srow = jbase + c * CROWS + prow;
    srow = srow < NFEAT ? srow : NFEAT - 1;       // clamp OOB (masked later)
    const int scol = (p & 511) ^ ((prow & 7) << 4);
    stage16((const char*)features + (size_t)srow * 512 + scol, &sbuf[buf][p]);
  };

  // ---- prologue, all VMEM loads issued BEFORE the stage DMAs so no consumer
  // forces vmcnt(0) across them. A staged per-M-tile: 8 float4 in flight max.
  bf8_t afrag[2][4];
#pragma unroll
  for (int mt = 0; mt < 2; ++mt) {
    const float* ap = inputs + (m0 + mt * 16 + l15) * DIM;
    float4 v0[4], v1[4];
#pragma unroll
    for (int ks = 0; ks < 4; ++ks) {
      const int k = ks * 32 + lg * 8;
      v0[ks] = *reinterpret_cast<const float4*>(ap + k);
      v1[ks] = *reinterpret_cast<const float4*>(ap + k + 4);
    }
#pragma unroll
    for (int ks = 0; ks < 4; ++ks)
      afrag[mt][ks] = pack8(v0[ks], v1[ks]);
  }

  // packed row metadata: meta = (self_gallery_row << 10) | target_label
  // (labels < 1000 fit in 10 bits; gallery row < 100000 fits in 22 bits)
  int meta[2][4];
#pragma unroll
  for (int mt = 0; mt < 2; ++mt)
#pragma unroll
    for (int rr = 0; rr < 4; ++rr) {
      const int row = m0 + mt * 16 + lg * 4 + rr;
      meta[mt][rr] = (idx[row] << 10) | targets[row];
    }

  // labels -> reg BEFORE stages (so the ds_write below waits only to depth 3)
  int labv = 0;
  if (tid < BN) {
    int jc = jbase + tid; jc = jc < NFEAT ? jc : NFEAT - 1;
    labv = flabels[jc];
  }

  stage_chunk(0, 0); stage_chunk(1, 1); stage_chunk(2, 2);

  if (tid < BN) slab[tid] = labv;

  float minpos[2][4], maxneg[2][4];
#pragma unroll
  for (int mt = 0; mt < 2; ++mt)
#pragma unroll
    for (int rr = 0; rr < 4; ++rr) { minpos[mt][rr] = FLT_BIG; maxneg[mt][rr] = -FLT_BIG; }

  asm volatile("s_waitcnt lgkmcnt(0)" ::: "memory");  // slab visible
  __builtin_amdgcn_s_barrier();
  CFENCE();

  // ---- main loop: wait(counted) -> barrier -> issue c+3 -> compute c
#pragma unroll
  for (int c = 0; c < NCHUNK; ++c) {
    // chunk c landed (this wave); outstanding = min(3, NCHUNK-1-c) chunks after
    if (c < NCHUNK - 2)      { WAITVM(2); }
    else if (c == NCHUNK - 2){ WAITVM(1); }
    else                     { WAITVM(0); }
    __builtin_amdgcn_s_barrier();   // all waves' chunk-c slices in LDS;
    CFENCE();                       // all waves done computing chunk c-1

    if (c + 3 < NCHUNK) stage_chunk((c + 3) & 3, c + 3);  // overwrite buf (c-1)

    const int  jcol   = c * CROWS + l15;
    const int  j      = jbase + jcol;
    const bool jvalid = (j < NFEAT);
    const int  labj   = slab[jcol];

    // B frags from swizzled LDS
    bf8_t bfrag[4];
    const char* rbase = &sbuf[c & 3][l15 * 512];
    const int   swz   = (l15 & 7) << 4;
#pragma unroll
    for (int ks = 0; ks < 4; ++ks) {
      const int b0 = ks * 128 + lg * 32;
      float4 v0 = *reinterpret_cast<const float4*>(rbase + ((b0)      ^ swz));
      float4 v1 = *reinterpret_cast<const float4*>(rbase + ((b0 + 16) ^ swz));
      bfrag[ks] = pack8(v0, v1);
    }

#pragma unroll
    for (int mt = 0; mt < 2; ++mt) {
      f32x4 acc = {0.f, 0.f, 0.f, 0.f};
#pragma unroll
      for (int ks = 0; ks < 4; ++ks)
        acc = mfma_bf16(afrag[mt][ks], bfrag[ks], acc);
#pragma unroll
      for (int rr = 0; rr < 4; ++rr) {
        const float s    = acc[rr];
        const int   m    = meta[mt][rr];
        const bool same  = (labj == (m & 1023));
        const bool posok = jvalid && same && (j != (m >> 10));
        const bool negok = jvalid && !same;
        minpos[mt][rr] = fminf(minpos[mt][rr], posok ? s :  FLT_BIG);
        maxneg[mt][rr] = fmaxf(maxneg[mt][rr], negok ? s : -FLT_BIG);
      }
    }
  }

  // Reduce over the 16 cols held across each 16-lane group; coalesced write
#pragma unroll
  for (int mt = 0; mt < 2; ++mt)
#pragma unroll
    for (int rr = 0; rr < 4; ++rr) {
      float mp = minpos[mt][rr], mn = maxneg[mt][rr];
#pragma unroll
      for (int m = 1; m < 16; m <<= 1) {
        mp = fminf(mp, __shfl_xor(mp, m, 64));
        mn = fmaxf(mn, __shfl_xor(mn, m, 64));
      }
      if (l15 == 0) {
        const int row = m0 + mt * 16 + lg * 4 + rr;
        ppos[blk * NBATCH + row] = mp;   // [blk][row]: contiguous per block
        pneg[blk * NBATCH + row] = mn;
      }
    }
}

// Kernel 2: one block per batch row; fold NBLK partials (L2-resident), hinge,
// atomic mean-accumulate into out[0] (zeroed via hipMemsetAsync).
__global__ __launch_bounds__(256) void triplet_reduce(
    const float* __restrict__ ppos, const float* __restrict__ pneg,
    float* __restrict__ out)
{
  const int r = blockIdx.x;
  const int t = threadIdx.x;
  float mp = FLT_BIG, mn = -FLT_BIG;
  for (int b = t; b < NBLK; b += 256) {
    mp = fminf(mp, ppos[b * NBATCH + r]);
    mn = fmaxf(mn, pneg[b * NBATCH + r]);
  }
#pragma unroll
  for (int m = 1; m < 64; m <<= 1) {
    mp = fminf(mp, __shfl_xor(mp, m, 64));
    mn = fmaxf(mn, __shfl_xor(mn, m, 64));
  }
  __shared__ float smp[4], smn[4];
  if ((t & 63) == 0) { smp[t >> 6] = mp; smn[t >> 6] = mn; }
  __syncthreads();
  if (t == 0) {
    mp = fminf(fminf(smp[0], smp[1]), fminf(smp[2], smp[3]));
    mn = fmaxf(fmaxf(smn[0], smn[1]), fmaxf(smn[2], smn[3]));
    float loss = mn - mp + MARGIN_F;
    loss = loss > 0.f ? loss : 0.f;
    atomicAdd(out, loss * (1.0f / NBATCH));
  }
}

extern "C" void kernel_launch(void* const* d_in, const int* in_sizes, int n_in,
                              void* d_out, int out_size, void* d_ws, size_t ws_size,
                              hipStream_t stream) {
  const float* inputs   = (const float*)d_in[0];
  const float* features = (const float*)d_in[1];
  const int*   targets  = (const int*)d_in[2];
  const int*   flabels  = (const int*)d_in[3];
  const int*   idx      = (const int*)d_in[4];
  float* out  = (float*)d_out;
  float* ppos = (float*)d_ws;                 // [NBLK][256]
  float* pneg = ppos + (size_t)NBLK * NBATCH; // [NBLK][256]  (~1.6 MB total)

  hipMemsetAsync(out, 0, sizeof(float), stream);   // K2 accumulates atomically
  triplet_partial<<<NBLK, 512, 0, stream>>>(inputs, features, targets, flabels, idx, ppos, pneg);
  triplet_reduce<<<NBATCH, 256, 0, stream>>>(ppos, pneg, out);
}

// Round 7
// 56.593 us; speedup vs baseline: 1.0086x; 1.0086x over previous
//
#include <hip/hip_runtime.h>

#define NFEAT   100000
#define NBATCH  256
#define DIM     128
#define MARGIN_F 0.5f
#define BN      128                       // feature rows per block
#define NBLK    ((NFEAT + BN - 1) / BN)   // 782
#define CROWS   16                        // feature rows per staged chunk
#define NCHUNK  (BN / CROWS)              // 8
#define NBUF    4                         // pipeline depth (LDS buffers)
#define CBYTES  (CROWS * DIM * 4)         // 8 KiB per chunk
#define FLT_BIG 3.402823466e+38f

typedef __bf16 bf8_t  __attribute__((ext_vector_type(8)));
typedef short  sh8_t  __attribute__((ext_vector_type(8)));
typedef float  f32x4  __attribute__((ext_vector_type(4)));

// f32 -> bf16 native cast: compiler emits v_cvt_pk_bf16_f32 pairs (RTNE).
__device__ __forceinline__ bf8_t pack8(float4 v0, float4 v1) {
  bf8_t r;
  r[0] = (__bf16)v0.x; r[1] = (__bf16)v0.y; r[2] = (__bf16)v0.z; r[3] = (__bf16)v0.w;
  r[4] = (__bf16)v1.x; r[5] = (__bf16)v1.y; r[6] = (__bf16)v1.z; r[7] = (__bf16)v1.w;
  return r;
}

// MFMA dispatch: works whether the builtin takes bf16-vectors or short-vectors
template <typename VA, typename VC>
__device__ __forceinline__ auto mfma_sel(VA a, VA b, VC c, int)
    -> decltype(__builtin_amdgcn_mfma_f32_16x16x32_bf16(a, b, c, 0, 0, 0)) {
  return __builtin_amdgcn_mfma_f32_16x16x32_bf16(a, b, c, 0, 0, 0);
}
template <typename VA, typename VC>
__device__ __forceinline__ VC mfma_sel(VA a, VA b, VC c, long) {
  return __builtin_amdgcn_mfma_f32_16x16x32_bf16(
      __builtin_bit_cast(sh8_t, a), __builtin_bit_cast(sh8_t, b), c, 0, 0, 0);
}
__device__ __forceinline__ f32x4 mfma_bf16(bf8_t a, bf8_t b, f32x4 c) {
  return mfma_sel(a, b, c, 0);
}

#if defined(__has_builtin)
#if __has_builtin(__builtin_amdgcn_global_load_lds)
#define HAVE_GLLDS 1
#endif
#endif

// 16B global -> LDS async DMA (no VGPR round-trip; counted by vmcnt).
__device__ __forceinline__ void stage16(const char* g, char* l) {
#ifdef HAVE_GLLDS
  __builtin_amdgcn_global_load_lds(
      (const __attribute__((address_space(1))) unsigned int*)g,
      (__attribute__((address_space(3))) unsigned int*)l, 16, 0, 0);
#else
  *reinterpret_cast<float4*>(l) = *reinterpret_cast<const float4*>(g);
#endif
}

#define WAITVM(N) asm volatile("s_waitcnt vmcnt(" #N ")" ::: "memory")
#define CFENCE()  asm volatile("" ::: "memory")

// Kernel 1: fused GEMM + masked min/max partial reduction, counted-vmcnt
// software pipeline (T4): 4 LDS chunk buffers, loads stay in flight across
// barriers (vmcnt never drained to 0 in the main loop).
// Block b: feature rows [b*128, b*128+128) in 8 chunks of 16. 8 waves; wave w
// owns batch rows [32w, 32w+32) (2 M-tiles). A-frags in VGPRs.
// __launch_bounds__(512, 2): 256-reg cap -> demand (~110) fits, NO SCRATCH.
// (512,4) = 128-reg cap caused ~36 regs/thread spilled; the scratch reloads'
// waitcnts drained behind the stage DMAs and serialized the pipeline (R5/R6).
// B staged f32 via global_load_lds with pre-swizzled source (linear LDS dest,
// rule 21); reads undo the XOR (byte ^= (row&7)<<4).
// MFMA 16x16x32 layouts (guide §3, m89/m91-verified):
//   A: lane l holds A[m0 + (l&15)][k0 + (l>>4)*8 + e]
//   B: lane l holds B[k0 + (l>>4)*8 + e][j0 + (l&15)]   (= features[j][k])
//   D: lane l reg r = sim[m0 + (l>>4)*4 + r][j0 + (l&15)]
__global__ __launch_bounds__(512, 2) void triplet_partial(
    const float* __restrict__ inputs, const float* __restrict__ features,
    const int* __restrict__ targets, const int* __restrict__ flabels,
    const int* __restrict__ idx,
    float* __restrict__ ppos, float* __restrict__ pneg,
    float* __restrict__ out)
{
  __shared__ char sbuf[NBUF][CBYTES];   // 32 KiB
  __shared__ int  slab[BN];             // labels for this block's 128 rows

  const int tid  = threadIdx.x;
  const int lane = tid & 63;
  const int wv   = tid >> 6;      // 0..7
  const int l15  = lane & 15;
  const int lg   = lane >> 4;     // 0..3
  const int m0   = wv * 32;
  const int blk  = blockIdx.x;
  const int jbase = blk * BN;

  // zero the atomic accumulator (K2 launches after K1 completes: no race).
  // Issued before all other VMEM so its completion folds into the A-load waits.
  if (blk == 0 && tid == 0) out[0] = 0.0f;

  // stage one 16-row chunk: 1 x 16B per thread, linear LDS dest,
  // pre-swizzled global source (inverse of the read-side XOR).
  auto stage_chunk = [&](int buf, int c) {
    const int p    = tid * 16;                    // LDS byte within chunk
    const int prow = p >> 9;                      // 0..15
    int srow = jbase + c * CROWS + prow;
    srow = srow < NFEAT ? srow : NFEAT - 1;       // clamp OOB (masked later)
    const int scol = (p & 511) ^ ((prow & 7) << 4);
    stage16((const char*)features + (size_t)srow * 512 + scol, &sbuf[buf][p]);
  };

  // ---- prologue: all VMEM loads issued BEFORE the stage DMAs so no consumer
  // forces vmcnt(0) across them.
  bf8_t afrag[2][4];
#pragma unroll
  for (int mt = 0; mt < 2; ++mt) {
    const float* ap = inputs + (m0 + mt * 16 + l15) * DIM;
    float4 v0[4], v1[4];
#pragma unroll
    for (int ks = 0; ks < 4; ++ks) {
      const int k = ks * 32 + lg * 8;
      v0[ks] = *reinterpret_cast<const float4*>(ap + k);
      v1[ks] = *reinterpret_cast<const float4*>(ap + k + 4);
    }
#pragma unroll
    for (int ks = 0; ks < 4; ++ks)
      afrag[mt][ks] = pack8(v0[ks], v1[ks]);
  }

  // packed row metadata: meta = (self_gallery_row << 10) | target_label
  // (labels < 1000 fit in 10 bits; gallery row < 100000 fits in 22 bits)
  int meta[2][4];
#pragma unroll
  for (int mt = 0; mt < 2; ++mt)
#pragma unroll
    for (int rr = 0; rr < 4; ++rr) {
      const int row = m0 + mt * 16 + lg * 4 + rr;
      meta[mt][rr] = (idx[row] << 10) | targets[row];
    }

  // labels -> reg BEFORE stages (consumer below then waits only vmcnt(3))
  int labv = 0;
  if (tid < BN) {
    int jc = jbase + tid; jc = jc < NFEAT ? jc : NFEAT - 1;
    labv = flabels[jc];
  }

  stage_chunk(0, 0); stage_chunk(1, 1); stage_chunk(2, 2);

  if (tid < BN) slab[tid] = labv;

  float minpos[2][4], maxneg[2][4];
#pragma unroll
  for (int mt = 0; mt < 2; ++mt)
#pragma unroll
    for (int rr = 0; rr < 4; ++rr) { minpos[mt][rr] = FLT_BIG; maxneg[mt][rr] = -FLT_BIG; }

  asm volatile("s_waitcnt lgkmcnt(0)" ::: "memory");  // slab visible
  __builtin_amdgcn_s_barrier();
  CFENCE();

  // ---- main loop: wait(counted) -> barrier -> issue c+3 -> compute c
#pragma unroll
  for (int c = 0; c < NCHUNK; ++c) {
    // outstanding DMAs at entry: chunks c..min(c+2, NCHUNK-1)
    if (c < NCHUNK - 2)      { WAITVM(2); }
    else if (c == NCHUNK - 2){ WAITVM(1); }
    else                     { WAITVM(0); }
    __builtin_amdgcn_s_barrier();   // all waves' chunk-c slices in LDS;
    CFENCE();                       // all waves done computing chunk c-1

    if (c + 3 < NCHUNK) stage_chunk((c + 3) & 3, c + 3);  // overwrite buf (c-1)

    const int  jcol   = c * CROWS + l15;
    const int  j      = jbase + jcol;
    const bool jvalid = (j < NFEAT);
    const int  labj   = slab[jcol];

    // B frags from swizzled LDS
    bf8_t bfrag[4];
    const char* rbase = &sbuf[c & 3][l15 * 512];
    const int   swz   = (l15 & 7) << 4;
#pragma unroll
    for (int ks = 0; ks < 4; ++ks) {
      const int b0 = ks * 128 + lg * 32;
      float4 v0 = *reinterpret_cast<const float4*>(rbase + ((b0)      ^ swz));
      float4 v1 = *reinterpret_cast<const float4*>(rbase + ((b0 + 16) ^ swz));
      bfrag[ks] = pack8(v0, v1);
    }

#pragma unroll
    for (int mt = 0; mt < 2; ++mt) {
      f32x4 acc = {0.f, 0.f, 0.f, 0.f};
#pragma unroll
      for (int ks = 0; ks < 4; ++ks)
        acc = mfma_bf16(afrag[mt][ks], bfrag[ks], acc);
#pragma unroll
      for (int rr = 0; rr < 4; ++rr) {
        const float s    = acc[rr];
        const int   m    = meta[mt][rr];
        const bool same  = (labj == (m & 1023));
        const bool posok = jvalid && same && (j != (m >> 10));
        const bool negok = jvalid && !same;
        minpos[mt][rr] = fminf(minpos[mt][rr], posok ? s :  FLT_BIG);
        maxneg[mt][rr] = fmaxf(maxneg[mt][rr], negok ? s : -FLT_BIG);
      }
    }
  }

  // Reduce over the 16 cols held across each 16-lane group; coalesced write
#pragma unroll
  for (int mt = 0; mt < 2; ++mt)
#pragma unroll
    for (int rr = 0; rr < 4; ++rr) {
      float mp = minpos[mt][rr], mn = maxneg[mt][rr];
#pragma unroll
      for (int m = 1; m < 16; m <<= 1) {
        mp = fminf(mp, __shfl_xor(mp, m, 64));
        mn = fmaxf(mn, __shfl_xor(mn, m, 64));
      }
      if (l15 == 0) {
        const int row = m0 + mt * 16 + lg * 4 + rr;
        ppos[blk * NBATCH + row] = mp;   // [blk][row]: contiguous per block
        pneg[blk * NBATCH + row] = mn;
      }
    }
}

// Kernel 2: one block per batch row; fold NBLK partials (L2-resident), hinge,
// atomic mean-accumulate into out[0] (zeroed by K1 block 0).
__global__ __launch_bounds__(256) void triplet_reduce(
    const float* __restrict__ ppos, const float* __restrict__ pneg,
    float* __restrict__ out)
{
  const int r = blockIdx.x;
  const int t = threadIdx.x;
  float mp = FLT_BIG, mn = -FLT_BIG;
  for (int b = t; b < NBLK; b += 256) {
    mp = fminf(mp, ppos[b * NBATCH + r]);
    mn = fmaxf(mn, pneg[b * NBATCH + r]);
  }
#pragma unroll
  for (int m = 1; m < 64; m <<= 1) {
    mp = fminf(mp, __shfl_xor(mp, m, 64));
    mn = fmaxf(mn, __shfl_xor(mn, m, 64));
  }
  __shared__ float smp[4], smn[4];
  if ((t & 63) == 0) { smp[t >> 6] = mp; smn[t >> 6] = mn; }
  __syncthreads();
  if (t == 0) {
    mp = fminf(fminf(smp[0], smp[1]), fminf(smp[2], smp[3]));
    mn = fmaxf(fmaxf(smn[0], smn[1]), fmaxf(smn[2], smn[3]));
    float loss = mn - mp + MARGIN_F;
    loss = loss > 0.f ? loss : 0.f;
    atomicAdd(out, loss * (1.0f / NBATCH));
  }
}

extern "C" void kernel_launch(void* const* d_in, const int* in_sizes, int n_in,
                              void* d_out, int out_size, void* d_ws, size_t ws_size,
                              hipStream_t stream) {
  const float* inputs   = (const float*)d_in[0];
  const float* features = (const float*)d_in[1];
  const int*   targets  = (const int*)d_in[2];
  const int*   flabels  = (const int*)d_in[3];
  const int*   idx      = (const int*)d_in[4];
  float* out  = (float*)d_out;
  float* ppos = (float*)d_ws;                 // [NBLK][256]
  float* pneg = ppos + (size_t)NBLK * NBATCH; // [NBLK][256]  (~1.6 MB total)

  triplet_partial<<<NBLK, 512, 0, stream>>>(inputs, features, targets, flabels, idx, ppos, pneg, out);
  triplet_reduce<<<NBATCH, 256, 0, stream>>>(ppos, pneg, out);
}

// Round 8
// 47.156 us; speedup vs baseline: 1.2105x; 1.2001x over previous
//
#include <hip/hip_runtime.h>

#define NFEAT   100000
#define NBATCH  256
#define DIM     128
#define MARGIN_F 0.5f
#define GRID    625                       // blocks; 625*10*16 = 100000 exactly
#define IPB     10                        // chunks per block
#define CROWS   16                        // feature rows per staged chunk
#define ROWS_PB (IPB * CROWS)             // 160 feature rows per block
#define NBUF    4                         // pipeline depth (LDS buffers)
#define CBYTES  (CROWS * DIM * 4)         // 8 KiB per chunk
#define FLT_BIG 3.402823466e+38f

typedef __bf16 bf8_t  __attribute__((ext_vector_type(8)));
typedef short  sh8_t  __attribute__((ext_vector_type(8)));
typedef float  f32x4  __attribute__((ext_vector_type(4)));

// f32 -> bf16 native cast: compiler emits v_cvt_pk_bf16_f32 pairs (RTNE).
__device__ __forceinline__ bf8_t pack8(float4 v0, float4 v1) {
  bf8_t r;
  r[0] = (__bf16)v0.x; r[1] = (__bf16)v0.y; r[2] = (__bf16)v0.z; r[3] = (__bf16)v0.w;
  r[4] = (__bf16)v1.x; r[5] = (__bf16)v1.y; r[6] = (__bf16)v1.z; r[7] = (__bf16)v1.w;
  return r;
}

// MFMA dispatch: works whether the builtin takes bf16-vectors or short-vectors
template <typename VA, typename VC>
__device__ __forceinline__ auto mfma_sel(VA a, VA b, VC c, int)
    -> decltype(__builtin_amdgcn_mfma_f32_16x16x32_bf16(a, b, c, 0, 0, 0)) {
  return __builtin_amdgcn_mfma_f32_16x16x32_bf16(a, b, c, 0, 0, 0);
}
template <typename VA, typename VC>
__device__ __forceinline__ VC mfma_sel(VA a, VA b, VC c, long) {
  return __builtin_amdgcn_mfma_f32_16x16x32_bf16(
      __builtin_bit_cast(sh8_t, a), __builtin_bit_cast(sh8_t, b), c, 0, 0, 0);
}
__device__ __forceinline__ f32x4 mfma_bf16(bf8_t a, bf8_t b, f32x4 c) {
  return mfma_sel(a, b, c, 0);
}

#if defined(__has_builtin)
#if __has_builtin(__builtin_amdgcn_global_load_lds)
#define HAVE_GLLDS 1
#endif
#endif

// 16B global -> LDS async DMA (no VGPR round-trip; counted by vmcnt).
__device__ __forceinline__ void stage16(const char* g, char* l) {
#ifdef HAVE_GLLDS
  __builtin_amdgcn_global_load_lds(
      (const __attribute__((address_space(1))) unsigned int*)g,
      (__attribute__((address_space(3))) unsigned int*)l, 16, 0, 0);
#else
  *reinterpret_cast<float4*>(l) = *reinterpret_cast<const float4*>(g);
#endif
}

#define WAITVM(N) asm volatile("s_waitcnt vmcnt(" #N ")" ::: "memory")
#define CFENCE()  asm volatile("" ::: "memory")

// Kernel 1: fused GEMM + masked min/max partial reduction.
// PERSISTENT-STYLE blocks (R8 change): 625 blocks, each owns 160 contiguous
// feature rows = 10 chunks of 16 -> ONE A-prologue + ONE pipeline fill per
// block, 10-deep steady state, single block generation (2.44 blocks/CU).
// Prior rounds (782-1563 tiny blocks x 8 iters, ~3 generations) were pinned
// at ~60us regardless of structure: per-block fixed costs dominated.
// Counted-vmcnt pipeline (T4): 4 LDS chunk buffers, DMAs stay in flight
// across barriers (vmcnt never drained to 0 mid-loop).
// 8 waves; wave w owns batch rows [32w,32w+32) (2 M-tiles). 100000 = 6250*16
// exactly -> no tail, no validity masking anywhere.
// B staged f32 via global_load_lds, pre-swizzled source (linear LDS dest,
// rule 21); reads undo the XOR (byte ^= (row&7)<<4).
// MFMA 16x16x32 layouts (guide §3, m89/m91-verified):
//   A: lane l holds A[m0 + (l&15)][k0 + (l>>4)*8 + e]
//   B: lane l holds B[k0 + (l>>4)*8 + e][j0 + (l&15)]   (= features[j][k])
//   D: lane l reg r = sim[m0 + (l>>4)*4 + r][j0 + (l&15)]
__global__ __launch_bounds__(512, 2) void triplet_partial(
    const float* __restrict__ inputs, const float* __restrict__ features,
    const int* __restrict__ targets, const int* __restrict__ flabels,
    const int* __restrict__ idx,
    float* __restrict__ ppos, float* __restrict__ pneg,
    float* __restrict__ out)
{
  __shared__ char sbuf[NBUF][CBYTES];   // 32 KiB
  __shared__ int  slab[ROWS_PB];        // labels for this block's 160 rows

  const int tid  = threadIdx.x;
  const int lane = tid & 63;
  const int wv   = tid >> 6;      // 0..7
  const int l15  = lane & 15;
  const int lg   = lane >> 4;     // 0..3
  const int m0   = wv * 32;
  const int blk  = blockIdx.x;
  const int rowbase = blk * ROWS_PB;   // first feature row of this block

  // zero the atomic accumulator (K2 launches after K1 completes: no race)
  if (blk == 0 && tid == 0) out[0] = 0.0f;

  // stage one 16-row chunk (local chunk id c): 1 x 16B per thread, linear LDS
  // dest, pre-swizzled global source (inverse of the read-side XOR).
  auto stage_chunk = [&](int buf, int c) {
    const int p    = tid * 16;                    // LDS byte within chunk
    const int prow = p >> 9;                      // 0..15
    const int srow = rowbase + c * CROWS + prow;  // always < NFEAT (exact fit)
    const int scol = (p & 511) ^ ((prow & 7) << 4);
    stage16((const char*)features + (size_t)srow * 512 + scol, &sbuf[buf][p]);
  };

  // ---- prologue: all reg-bound VMEM issued BEFORE the stage DMAs so no
  // consumer forces vmcnt(0) across them.
  bf8_t afrag[2][4];
#pragma unroll
  for (int mt = 0; mt < 2; ++mt) {
    const float* ap = inputs + (m0 + mt * 16 + l15) * DIM;
    float4 v0[4], v1[4];
#pragma unroll
    for (int ks = 0; ks < 4; ++ks) {
      const int k = ks * 32 + lg * 8;
      v0[ks] = *reinterpret_cast<const float4*>(ap + k);
      v1[ks] = *reinterpret_cast<const float4*>(ap + k + 4);
    }
#pragma unroll
    for (int ks = 0; ks < 4; ++ks)
      afrag[mt][ks] = pack8(v0[ks], v1[ks]);
  }

  // packed row metadata: meta = (self_gallery_row << 10) | target_label
  // (labels < 1000 fit in 10 bits; gallery row < 100000 fits in 22 bits)
  int meta[2][4];
#pragma unroll
  for (int mt = 0; mt < 2; ++mt)
#pragma unroll
    for (int rr = 0; rr < 4; ++rr) {
      const int row = m0 + mt * 16 + lg * 4 + rr;
      meta[mt][rr] = (idx[row] << 10) | targets[row];
    }

  // labels -> reg BEFORE stages (consumer below then waits only vmcnt(3))
  int labv = 0;
  if (tid < ROWS_PB) labv = flabels[rowbase + tid];

  stage_chunk(0, 0); stage_chunk(1, 1); stage_chunk(2, 2);

  if (tid < ROWS_PB) slab[tid] = labv;

  float minpos[2][4], maxneg[2][4];
#pragma unroll
  for (int mt = 0; mt < 2; ++mt)
#pragma unroll
    for (int rr = 0; rr < 4; ++rr) { minpos[mt][rr] = FLT_BIG; maxneg[mt][rr] = -FLT_BIG; }

  asm volatile("s_waitcnt lgkmcnt(0)" ::: "memory");  // slab visible
  __builtin_amdgcn_s_barrier();
  CFENCE();

  // ---- main loop: wait(counted) -> barrier -> issue c+3 -> compute c
#pragma unroll
  for (int c = 0; c < IPB; ++c) {
    // outstanding DMAs at entry: chunks c..min(c+2, IPB-1)
    if (c < IPB - 2)      { WAITVM(2); }
    else if (c == IPB - 2){ WAITVM(1); }
    else                  { WAITVM(0); }
    __builtin_amdgcn_s_barrier();   // all waves' chunk-c slices in LDS;
    CFENCE();                       // all waves done computing chunk c-1

    if (c + 3 < IPB) stage_chunk((c + 3) & 3, c + 3);  // overwrite buf (c-1)

    const int jcol = c * CROWS + l15;     // 0..159
    const int j    = rowbase + jcol;
    const int labj = slab[jcol];

    // B frags from swizzled LDS
    bf8_t bfrag[4];
    const char* rbase = &sbuf[c & 3][l15 * 512];
    const int   swz   = (l15 & 7) << 4;
#pragma unroll
    for (int ks = 0; ks < 4; ++ks) {
      const int b0 = ks * 128 + lg * 32;
      float4 v0 = *reinterpret_cast<const float4*>(rbase + ((b0)      ^ swz));
      float4 v1 = *reinterpret_cast<const float4*>(rbase + ((b0 + 16) ^ swz));
      bfrag[ks] = pack8(v0, v1);
    }

#pragma unroll
    for (int mt = 0; mt < 2; ++mt) {
      f32x4 acc = {0.f, 0.f, 0.f, 0.f};
#pragma unroll
      for (int ks = 0; ks < 4; ++ks)
        acc = mfma_bf16(afrag[mt][ks], bfrag[ks], acc);
#pragma unroll
      for (int rr = 0; rr < 4; ++rr) {
        const float s    = acc[rr];
        const int   m    = meta[mt][rr];
        const bool same  = (labj == (m & 1023));
        const bool self  = (j == (m >> 10));
        minpos[mt][rr] = fminf(minpos[mt][rr], (same && !self) ? s : FLT_BIG);
        maxneg[mt][rr] = fmaxf(maxneg[mt][rr], same ? -FLT_BIG : s);
      }
    }
  }

  // Reduce over the 16 cols held across each 16-lane group; coalesced write
#pragma unroll
  for (int mt = 0; mt < 2; ++mt)
#pragma unroll
    for (int rr = 0; rr < 4; ++rr) {
      float mp = minpos[mt][rr], mn = maxneg[mt][rr];
#pragma unroll
      for (int m = 1; m < 16; m <<= 1) {
        mp = fminf(mp, __shfl_xor(mp, m, 64));
        mn = fmaxf(mn, __shfl_xor(mn, m, 64));
      }
      if (l15 == 0) {
        const int row = m0 + mt * 16 + lg * 4 + rr;
        ppos[blk * NBATCH + row] = mp;   // [blk][row]: contiguous per block
        pneg[blk * NBATCH + row] = mn;
      }
    }
}

// Kernel 2: one block per batch row; fold GRID partials (L2-resident), hinge,
// atomic mean-accumulate into out[0] (zeroed by K1 block 0).
__global__ __launch_bounds__(256) void triplet_reduce(
    const float* __restrict__ ppos, const float* __restrict__ pneg,
    float* __restrict__ out)
{
  const int r = blockIdx.x;
  const int t = threadIdx.x;
  float mp = FLT_BIG, mn = -FLT_BIG;
  for (int b = t; b < GRID; b += 256) {
    mp = fminf(mp, ppos[b * NBATCH + r]);
    mn = fmaxf(mn, pneg[b * NBATCH + r]);
  }
#pragma unroll
  for (int m = 1; m < 64; m <<= 1) {
    mp = fminf(mp, __shfl_xor(mp, m, 64));
    mn = fmaxf(mn, __shfl_xor(mn, m, 64));
  }
  __shared__ float smp[4], smn[4];
  if ((t & 63) == 0) { smp[t >> 6] = mp; smn[t >> 6] = mn; }
  __syncthreads();
  if (t == 0) {
    mp = fminf(fminf(smp[0], smp[1]), fminf(smp[2], smp[3]));
    mn = fmaxf(fmaxf(smn[0], smn[1]), fmaxf(smn[2], smn[3]));
    float loss = mn - mp + MARGIN_F;
    loss = loss > 0.f ? loss : 0.f;
    atomicAdd(out, loss * (1.0f / NBATCH));
  }
}

extern "C" void kernel_launch(void* const* d_in, const int* in_sizes, int n_in,
                              void* d_out, int out_size, void* d_ws, size_t ws_size,
                              hipStream_t stream) {
  const float* inputs   = (const float*)d_in[0];
  const float* features = (const float*)d_in[1];
  const int*   targets  = (const int*)d_in[2];
  const int*   flabels  = (const int*)d_in[3];
  const int*   idx      = (const int*)d_in[4];
  float* out  = (float*)d_out;
  float* ppos = (float*)d_ws;                 // [GRID][256]
  float* pneg = ppos + (size_t)GRID * NBATCH; // [GRID][256]  (~1.28 MB total)

  triplet_partial<<<GRID, 512, 0, stream>>>(inputs, features, targets, flabels, idx, ppos, pneg, out);
  triplet_reduce<<<NBATCH, 256, 0, stream>>>(ppos, pneg, out);
}